// Round 1
// 1014.053 us; speedup vs baseline: 1.1755x; 1.1755x over previous
//
#include <hip/hip_runtime.h>

#define DEVI __device__ __forceinline__

typedef __bf16 bf16x8 __attribute__((ext_vector_type(8)));
typedef float f32x4 __attribute__((ext_vector_type(4)));
typedef unsigned short u16;
typedef long long i64;

constexpr int B_ = 4;
constexpr int C_ = 1024;
constexpr int CI_ = 512;
constexpr int C3_ = 3 * CI_;       // 1536 fused conv output cols
constexpr int N_ = 16 * 28 * 28;   // 12544 = 49*256
constexpr int M_ = 8 * 14 * 14;    // 1568
constexpr int MP_ = 1792;          // 7*256 padded (was 13*128)

DEVI u16 f2bf(float f) { __bf16 b = (__bf16)f; return __builtin_bit_cast(u16, b); }
DEVI float bf2f(u16 u) { return (float)__builtin_bit_cast(__bf16, u); }

#define GLOBAL_AS __attribute__((address_space(1)))
#define LDS_AS __attribute__((address_space(3)))

DEVI void load16(const u16* g, u16* l) {
  __builtin_amdgcn_global_load_lds((const GLOBAL_AS void*)g, (LDS_AS void*)l, 16, 0, 0);
}

// vmcnt(N)+barrier sync cluster. "memory" clobbers pin plain LDS loads and the
// global_load_lds intrinsics on their program-order side of the cluster.
#define SYNC_V(N)                                        \
  asm volatile("s_waitcnt vmcnt(" #N ")" ::: "memory");  \
  __builtin_amdgcn_s_barrier();                          \
  asm volatile("" ::: "memory");

// ---------------------------------------------------------------------------
// Universal batched TN GEMM, 256x256 tile, BK=64, 512 threads (8 waves, 2Mx4N),
// MFMA 16x16x32 bf16, counted-vmcnt multi-phase schedule (T3+T4+T2+T5).
//
// LDS (128 KiB): [buf:2][mat A|B][kh:2][row:256][8 bf16 x 4 slots]
//   kh-block = 16 KiB, linear so global_load_lds (wave base + lane*16) works.
//   Bank swizzle: 16B slot index XORed with (row>>1)&3 — applied on the
//   GLOBAL source (stage) and the ds_read address (both-sides involution).
//   => per-wave ds_read_b128 lands 2 lanes/bank = conflict-free (m136).
//
// Per K-tile t: 4 phases (mh0/kh0, mh1/kh0, mh0/kh1, mh1/kh1), 16 MFMA each.
// Stage schedule (2 global_load_lds inst/phase, 6-phase prefetch lead):
//   P1: U1_{t+1}.A   P2: U1_{t+1}.B  vmcnt(8)+bar
//   P3: U0_{t+2}.A   P4: U0_{t+2}.B  vmcnt(8)+bar
// Issue-order proof: at each sync exactly the youngest 8 load-insts (next 1.5
// tiles) stay in flight; the kh-half read next is always older => landed.
// WAR: each overwritten slot's last read precedes the barrier before its issue.
// vmcnt(0) only once, in the tail (last 2 tiles computed without stages).
//
// MODE 0: bf16 out = acc + e0[col];  MODE 1: bf16 out = acc
// MODE 3: fp32 out = (acc+e0[row])*e1[row]*rsqrt(1+eps) + e2[row] + xres
// ---------------------------------------------------------------------------
template <int MODE>
__global__ __launch_bounds__(512, 2)
void gemm_tn(const u16* __restrict__ A, const u16* __restrict__ Bm,
             void* __restrict__ Cp, int K, int lda, int ldb, int ldc,
             i64 sA, i64 sB, i64 sC,
             const float* __restrict__ e0, const float* __restrict__ e1,
             const float* __restrict__ e2, const float* __restrict__ xres, i64 sX) {
  __shared__ u16 sm[2 * 32768];  // 128 KiB
  const int b = blockIdx.z;
  A += (size_t)b * sA;
  Bm += (size_t)b * sB;
  const size_t cbase = (size_t)b * sC;
  if constexpr (MODE == 3) xres += (size_t)b * sX;

  const int tid = threadIdx.x;
  const int lane = tid & 63;
  const int wave = tid >> 6;  // 0..7
  const int wm = wave >> 2;   // 0..1 (M half)
  const int wn = wave & 3;    // 0..3 (N quarter)
  const int i0 = blockIdx.y * 256;
  const int j0 = blockIdx.x * 256;

  // ---- staging addresses (pre-swizzled global source, linear LDS dest) ----
  const int rs = tid >> 2;                                // chunk row 0..127
  const int swz = ((tid & 3) ^ ((rs >> 1) & 3)) * 8;      // swizzled col elems
  const u16* Ag0 = A + (size_t)(i0 + rs) * lda + swz;
  const u16* Bg0 = Bm + (size_t)(j0 + rs) * ldb + swz;
  const i64 ldA128 = (i64)128 * lda;
  const i64 ldB128 = (i64)128 * ldb;
  u16* ldsT = sm + tid * 8;  // per-wave: base + lane*16B (linear)

  auto stA = [&](int buf, int kh, int k0) {
    const u16* s = Ag0 + k0 + kh * 32;
    u16* d = ldsT + buf * 32768 + kh * 8192;
    load16(s, d);
    load16(s + ldA128, d + 4096);
  };
  auto stB = [&](int buf, int kh, int k0) {
    const u16* s = Bg0 + k0 + kh * 32;
    u16* d = ldsT + buf * 32768 + 16384 + kh * 8192;
    load16(s, d);
    load16(s + ldB128, d + 4096);
  };

  // ---- fragment read addressing ----
  const int l15 = lane & 15;
  const int slR = (((lane >> 4) ^ ((l15 >> 1) & 3)) * 8);  // swizzled 16B slot
  const int arow = wm * 128 + l15;  // + frag*16
  const int brow = wn * 64 + l15;   // + frag*16

  f32x4 acc[8][4] = {};

// one K-half: load 4 B-frags once, reuse across both mh halves (12 ds_reads)
#define KHALF(BUF, KH, S1, S2, SYNC)                                           \
  {                                                                            \
    const u16* Ab_ = sm + (BUF) * 32768 + (KH) * 8192;                         \
    const u16* Bb_ = Ab_ + 16384;                                              \
    bf16x8 bv[4], a0[4], a1[4];                                                \
    _Pragma("unroll") for (int n = 0; n < 4; ++n)                              \
        bv[n] = *(const bf16x8*)&Bb_[(brow + n * 16) * 32 + slR];              \
    _Pragma("unroll") for (int f = 0; f < 4; ++f)                              \
        a0[f] = *(const bf16x8*)&Ab_[(arow + f * 16) * 32 + slR];              \
    S1;                                                                        \
    __builtin_amdgcn_s_setprio(1);                                             \
    _Pragma("unroll") for (int f = 0; f < 4; ++f)                              \
        _Pragma("unroll") for (int n = 0; n < 4; ++n)                          \
            acc[f][n] = __builtin_amdgcn_mfma_f32_16x16x32_bf16(               \
                a0[f], bv[n], acc[f][n], 0, 0, 0);                             \
    __builtin_amdgcn_s_setprio(0);                                             \
    _Pragma("unroll") for (int f = 0; f < 4; ++f)                              \
        a1[f] = *(const bf16x8*)&Ab_[(arow + (f + 4) * 16) * 32 + slR];        \
    S2;                                                                        \
    __builtin_amdgcn_s_setprio(1);                                             \
    _Pragma("unroll") for (int f = 0; f < 4; ++f)                              \
        _Pragma("unroll") for (int n = 0; n < 4; ++n)                          \
            acc[f + 4][n] = __builtin_amdgcn_mfma_f32_16x16x32_bf16(           \
                a1[f], bv[n], acc[f + 4][n], 0, 0, 0);                         \
    __builtin_amdgcn_s_setprio(0);                                             \
    SYNC                                                                       \
  }

  const int NT = K >> 6;  // always >= 2 here (min K = 512)

  // prologue: U0_0(A,B), U1_0(A,B), U0_1(A,B) = 12 load-insts.
  // vmcnt(8) => first 4 (U0_0) landed, which is all tile-0/kh0 needs.
  stA(0, 0, 0); stB(0, 0, 0);
  stA(0, 1, 0); stB(0, 1, 0);
  stA(1, 0, 64); stB(1, 0, 64);
  SYNC_V(8);

  for (int t = 0; t < NT - 2; ++t) {
    const int bc = t & 1;
    const int k0 = t * 64;
    KHALF(bc, 0, stA(bc ^ 1, 1, k0 + 64), stB(bc ^ 1, 1, k0 + 64), SYNC_V(8));
    KHALF(bc, 1, stA(bc, 0, k0 + 128), stB(bc, 0, k0 + 128), SYNC_V(8));
  }
  {  // tail: stage U1_{NT-1}, drain once, compute last 2 tiles
    const int bc = (NT - 2) & 1;
    stA(bc ^ 1, 1, (NT - 1) * 64);
    stB(bc ^ 1, 1, (NT - 1) * 64);
    SYNC_V(0);
    KHALF(bc, 0, (void)0, (void)0, );
    KHALF(bc, 1, (void)0, (void)0, );
    KHALF(bc ^ 1, 0, (void)0, (void)0, );
    KHALF(bc ^ 1, 1, (void)0, (void)0, );
  }
#undef KHALF

  // C/D layout (verified m89/m91): col = lane&15, row = (lane>>4)*4 + reg
  const int rr0 = i0 + wm * 128 + ((lane >> 4) << 2);
  const int cc0 = j0 + wn * 64 + (lane & 15);
  float* Cf = (float*)Cp;
  u16* Cs = (u16*)Cp;
#pragma unroll
  for (int mi = 0; mi < 8; ++mi) {
#pragma unroll
    for (int ni = 0; ni < 4; ++ni) {
      const int col = cc0 + ni * 16;
#pragma unroll
      for (int r = 0; r < 4; ++r) {
        const int row = rr0 + mi * 16 + r;
        const size_t idx = cbase + (size_t)row * ldc + col;
        float v = acc[mi][ni][r];
        if constexpr (MODE == 0) {
          Cs[idx] = f2bf(v + e0[col]);
        } else if constexpr (MODE == 1) {
          Cs[idx] = f2bf(v);
        } else {
          const float sc = e1[row] * rsqrtf(1.0f + 1e-5f);
          Cf[idx] = (v + e0[row]) * sc + e2[row] + xres[(size_t)row * ldc + col];
        }
      }
    }
  }
}

// x (b,C,N) fp32 -> Xt (b,N,C) bf16 (tiled transpose-cast); z = batch
__global__ __launch_bounds__(256)
void transpose_cast_x(const float* __restrict__ src, u16* __restrict__ dst) {
  __shared__ u16 tile[32][33];
  const size_t so = (size_t)blockIdx.z * C_ * N_;
  const int n0 = blockIdx.x * 32;
  const int c0 = blockIdx.y * 32;
  const int tx = threadIdx.x & 31;
  const int ty = threadIdx.x >> 5;  // 0..7
#pragma unroll
  for (int rr = 0; rr < 32; rr += 8)
    tile[ty + rr][tx] = f2bf(src[so + (size_t)(c0 + ty + rr) * N_ + n0 + tx]);
  __syncthreads();
#pragma unroll
  for (int rr = 0; rr < 32; rr += 8)
    dst[so + (size_t)(n0 + ty + rr) * C_ + c0 + tx] = tile[tx][ty + rr];
}

// bf16 transpose per batch: src (b, MP_, CI_) -> dst (b, CI_, MP_)
__global__ __launch_bounds__(256)
void transpose_bf16(const u16* __restrict__ src, u16* __restrict__ dst) {
  __shared__ u16 tile[32][33];
  const int b = blockIdx.z;
  const int c0 = blockIdx.x * 32;  // over CI_
  const int r0 = blockIdx.y * 32;  // over MP_
  const int tx = threadIdx.x & 31;
  const int ty = threadIdx.x >> 5;
#pragma unroll
  for (int rr = 0; rr < 32; rr += 8)
    tile[ty + rr][tx] = src[(size_t)b * MP_ * CI_ + (size_t)(r0 + ty + rr) * CI_ + c0 + tx];
  __syncthreads();
#pragma unroll
  for (int rr = 0; rr < 32; rr += 8)
    dst[(size_t)b * CI_ * MP_ + (size_t)(c0 + ty + rr) * MP_ + r0 + tx] = tile[tx][ty + rr];
}

// cast weights fp32->bf16 into fused layout: wcat rows [theta; g; phi], plus Ww
__global__ __launch_bounds__(256)
void cast_weights(const float* s0, const float* s1, const float* s2, const float* s3,
                  u16* d0, u16* d1, u16* d2, u16* d3) {
  const int idx = blockIdx.x * 256 + threadIdx.x;  // 524288 elems each
  const float* s;
  u16* d;
  switch (blockIdx.y) {
    case 0: s = s0; d = d0; break;
    case 1: s = s1; d = d1; break;
    case 2: s = s2; d = d2; break;
    default: s = s3; d = d3; break;
  }
  d[idx] = f2bf(s[idx]);
}

// pack [theta_b; g_b; phi_b] -> ebias fp32[1536]
__global__ __launch_bounds__(256)
void concat_bias(const float* tb, const float* gb, const float* pb, float* dst) {
  const int i = blockIdx.x * 256 + threadIdx.x;
  if (i >= C3_) return;
  dst[i] = (i < CI_) ? tb[i] : (i < 2 * CI_) ? gb[i - CI_] : pb[i - 2 * CI_];
}

// maxpool2 over (T,H,W): reads CO (b, N_, C3_) at col offset 512(g)/1024(phi),
// writes (b, MP_, CI_); pad rows (m >= M_) zeroed. grid: (MP_*CI_/256, 2, G)
__global__ __launch_bounds__(256)
void pool2(const u16* __restrict__ CO, u16* __restrict__ Gp, u16* __restrict__ Pp) {
  const int b = blockIdx.z;
  const int which = blockIdx.y;  // 0 = g, 1 = phi
  const u16* src = CO + (size_t)b * N_ * C3_ + CI_ + which * CI_;
  u16* dst = (which ? Pp : Gp) + (size_t)b * MP_ * CI_;
  const int idx = blockIdx.x * 256 + threadIdx.x;  // over MP_*CI_
  const int m = idx >> 9;
  const int ci = idx & 511;
  if (m >= M_) { dst[idx] = 0; return; }
  const int t = m / 196, r = m % 196, h = r / 14, w = r % 14;
  const int nb = 2 * t * 784 + 2 * h * 28 + 2 * w;
  float mx = -1e30f;
#pragma unroll
  for (int dt = 0; dt < 2; ++dt)
#pragma unroll
    for (int dh = 0; dh < 2; ++dh)
#pragma unroll
      for (int dw = 0; dw < 2; ++dw)
        mx = fmaxf(mx, bf2f(src[(size_t)(nb + dt * 784 + dh * 28 + dw) * C3_ + ci]));
  dst[idx] = f2bf(mx);
}

// in-place row softmax (bf16) over m<M_ of F (b, N_, MP_); pad cols -> 0
__global__ __launch_bounds__(256)
void softmax_k(u16* __restrict__ F) {
  u16* row = F + ((size_t)blockIdx.y * N_ + blockIdx.x) * MP_;
  const int tid = threadIdx.x;
  float v[7];
  float mx = -1e30f;
#pragma unroll
  for (int it = 0; it < 7; ++it) {
    const int j = tid + it * 256;
    v[it] = (j < M_) ? bf2f(row[j]) : -1e30f;
    mx = fmaxf(mx, v[it]);
  }
#pragma unroll
  for (int off = 32; off >= 1; off >>= 1) mx = fmaxf(mx, __shfl_xor(mx, off));
  __shared__ float redm[4], reds[4];
  const int wv = tid >> 6;
  if ((tid & 63) == 0) redm[wv] = mx;
  __syncthreads();
  mx = fmaxf(fmaxf(redm[0], redm[1]), fmaxf(redm[2], redm[3]));
  float s = 0.f;
#pragma unroll
  for (int it = 0; it < 7; ++it) {
    const int j = tid + it * 256;
    v[it] = (j < M_) ? __expf(v[it] - mx) : 0.f;
    s += v[it];
  }
#pragma unroll
  for (int off = 32; off >= 1; off >>= 1) s += __shfl_xor(s, off);
  if ((tid & 63) == 0) reds[wv] = s;
  __syncthreads();
  s = reds[0] + reds[1] + reds[2] + reds[3];
  const float inv = 1.f / s;
#pragma unroll
  for (int it = 0; it < 7; ++it) {
    const int j = tid + it * 256;
    if (j < MP_) row[j] = f2bf(v[it] * inv);
  }
}

extern "C" void kernel_launch(void* const* d_in, const int* in_sizes, int n_in,
                              void* d_out, int out_size, void* d_ws, size_t ws_size,
                              hipStream_t stream) {
  (void)in_sizes; (void)n_in; (void)out_size;
  const float* x    = (const float*)d_in[0];
  const float* g_w  = (const float*)d_in[1];
  const float* g_b  = (const float*)d_in[2];
  const float* th_w = (const float*)d_in[3];
  const float* th_b = (const float*)d_in[4];
  const float* ph_w = (const float*)d_in[5];
  const float* ph_b = (const float*)d_in[6];
  const float* w_w  = (const float*)d_in[7];
  const float* w_b  = (const float*)d_in[8];
  const float* bn_g = (const float*)d_in[9];
  const float* bn_b = (const float*)d_in[10];
  float* out = (float*)d_out;

  auto align256 = [](size_t b) { return (b + 255) & ~(size_t)255; };
  const size_t fixed_bytes = align256((size_t)C3_ * C_ * 2) + align256((size_t)C_ * CI_ * 2) +
                             align256((size_t)C3_ * 4);
  const size_t per_batch = align256((size_t)N_ * C_ * 2)    // Xt
                         + align256((size_t)N_ * C3_ * 2)   // CO
                         + align256((size_t)N_ * MP_ * 2)   // F / P
                         + align256((size_t)N_ * CI_ * 2)   // Yb
                         + 3 * align256((size_t)MP_ * CI_ * 2);  // Gp, Pp, Gp2
  int G = 4;
  while (G > 1 && fixed_bytes + (size_t)G * per_batch > ws_size) G >>= 1;

  char* ws = (char*)d_ws;
  size_t off = 0;
  auto alloc = [&](size_t bytes) -> void* {
    void* p = ws + off;
    off += align256(bytes);
    return p;
  };
  u16* wcat = (u16*)alloc((size_t)C3_ * C_ * 2);   // rows: [theta; g; phi]
  u16* wwB  = (u16*)alloc((size_t)C_ * CI_ * 2);
  float* eb = (float*)alloc((size_t)C3_ * 4);
  u16* Xt  = (u16*)alloc((size_t)G * N_ * C_ * 2);
  u16* CO  = (u16*)alloc((size_t)G * N_ * C3_ * 2);
  u16* Fb  = (u16*)alloc((size_t)G * N_ * MP_ * 2);  // logits, then probs in-place
  u16* Yb  = (u16*)alloc((size_t)G * N_ * CI_ * 2);
  u16* Gp  = (u16*)alloc((size_t)G * MP_ * CI_ * 2);
  u16* Pp  = (u16*)alloc((size_t)G * MP_ * CI_ * 2);
  u16* Gp2 = (u16*)alloc((size_t)G * CI_ * MP_ * 2);

  const dim3 blk(256);
  const dim3 gblk(512);
  cast_weights<<<dim3(2048, 4), blk, 0, stream>>>(
      th_w, g_w, ph_w, w_w, wcat, wcat + (size_t)CI_ * C_, wcat + (size_t)2 * CI_ * C_, wwB);
  concat_bias<<<dim3(6), blk, 0, stream>>>(th_b, g_b, ph_b, eb);

  for (int bg = 0; bg < B_; bg += G) {
    const float* xg = x + (size_t)bg * C_ * N_;
    float* og = out + (size_t)bg * C_ * N_;
    transpose_cast_x<<<dim3(N_ / 32, C_ / 32, G), blk, 0, stream>>>(xg, Xt);
    // fused 1x1 convs: CO(G*N, C3) = Xt(G*N, C) . wcat(C3, C)^T + eb  (batches stacked)
    gemm_tn<0><<<dim3(C3_ / 256, G * N_ / 256, 1), gblk, 0, stream>>>(
        Xt, wcat, CO, C_, C_, C_, C3_, 0, 0, 0, eb, nullptr, nullptr, nullptr, 0);
    pool2<<<dim3(MP_ * CI_ / 256, 2, G), blk, 0, stream>>>(CO, Gp, Pp);
    transpose_bf16<<<dim3(CI_ / 32, MP_ / 32, G), blk, 0, stream>>>(Gp, Gp2);
    // logits: F(b; N, MP) = Th(b; N, CI [lda=C3]) . Pp(b; MP, CI)^T
    gemm_tn<1><<<dim3(MP_ / 256, N_ / 256, G), gblk, 0, stream>>>(
        CO, Pp, Fb, CI_, C3_, CI_, MP_,
        (i64)N_ * C3_, (i64)MP_ * CI_, (i64)N_ * MP_, nullptr, nullptr, nullptr, nullptr, 0);
    softmax_k<<<dim3(N_, G), blk, 0, stream>>>(Fb);
    // y: Yb(b; N, CI) = P(b; N, MP) . Gp2(b; CI, MP)^T
    gemm_tn<1><<<dim3(CI_ / 256, N_ / 256, G), gblk, 0, stream>>>(
        Fb, Gp2, Yb, MP_, MP_, MP_, CI_,
        (i64)N_ * MP_, (i64)CI_ * MP_, (i64)N_ * CI_, nullptr, nullptr, nullptr, nullptr, 0);
    // out: (b; C, N) = Ww(C, CI) . Yb(b; N, CI)^T, epilogue bias/BN/residual
    gemm_tn<3><<<dim3(N_ / 256, C_ / 256, G), gblk, 0, stream>>>(
        wwB, Yb, og, CI_, CI_, CI_, N_,
        0, (i64)N_ * CI_, (i64)C_ * N_, w_b, bn_g, bn_b, xg, (i64)C_ * N_);
  }
}

// Round 2
// 992.021 us; speedup vs baseline: 1.2016x; 1.0222x over previous
//
#include <hip/hip_runtime.h>

#define DEVI __device__ __forceinline__

typedef __bf16 bf16x8 __attribute__((ext_vector_type(8)));
typedef float f32x4 __attribute__((ext_vector_type(4)));
typedef unsigned short u16;
typedef u16 u16x8v __attribute__((ext_vector_type(8)));
typedef long long i64;

constexpr int B_ = 4;
constexpr int C_ = 1024;
constexpr int CI_ = 512;
constexpr int C3_ = 3 * CI_;       // 1536 fused conv output cols
constexpr int N_ = 16 * 28 * 28;   // 12544 = 49*256
constexpr int M_ = 8 * 14 * 14;    // 1568 = 196*8
constexpr int MP_ = 1792;          // 7*256 padded

DEVI u16 f2bf(float f) { __bf16 b = (__bf16)f; return __builtin_bit_cast(u16, b); }
DEVI float bf2f(u16 u) { return (float)__builtin_bit_cast(__bf16, u); }

#define GLOBAL_AS __attribute__((address_space(1)))
#define LDS_AS __attribute__((address_space(3)))

DEVI void load16(const u16* g, u16* l) {
  __builtin_amdgcn_global_load_lds((const GLOBAL_AS void*)g, (LDS_AS void*)l, 16, 0, 0);
}

// counted-vmcnt + barrier sync; sched_barrier(0) keeps MFMAs from hoisting
// above the barrier (rule #18) while reads stay pinned before it by the
// "memory" clobber on the vmcnt asm.
#define SYNC_V(N)                                        \
  asm volatile("s_waitcnt vmcnt(" #N ")" ::: "memory");  \
  __builtin_amdgcn_s_barrier();                          \
  __builtin_amdgcn_sched_barrier(0);

// ---------------------------------------------------------------------------
// Universal batched TN GEMM, 256x256 tile, BK=64, 512 threads (8 waves, 2Mx4N),
// MFMA 16x16x32 bf16, counted-vmcnt multi-phase schedule (T1+T2+T3+T4+T5).
//
// LDS (128 KiB): [buf:2][mat A|B][kh:2][row:256][8 bf16 x 4 slots]
//   Bank swizzle: 16B slot index XORed with (row>>1)&3 on BOTH the global
//   staging source and the ds_read address (rule #21 involution).
//
// KHALF phase shape (m201 style — reads BEFORE the sync so ds latency hides
// under the vmcnt/barrier wait):
//   12 ds_reads of current half-tile (data guaranteed by an EARLIER sync)
//   4 global_load_lds stage insts (next unit)
//   s_waitcnt vmcnt(8); s_barrier; sched_barrier(0)
//   setprio(1); 32 MFMA; setprio(0)
// Guarantee chain (4 load-insts per KHALF, counted-8 window): reads of U0_t
// are covered by the sync inside KHALF(t-1,kh1); reads of U1_t by the sync
// inside KHALF(t,kh0). WAR skew <= 1 barrier. Tail drains 8 -> 4 -> 0.
//
// MODE 0: bf16 out = acc + e0[col];  MODE 1: bf16 out = acc
// MODE 3: fp32 out = (acc+e0[row])*e1[row]*rsqrt(1+eps) + e2[row] + xres
// ---------------------------------------------------------------------------
template <int MODE>
__global__ __launch_bounds__(512, 2)
void gemm_tn(const u16* __restrict__ A, const u16* __restrict__ Bm,
             void* __restrict__ Cp, int K, int lda, int ldb, int ldc,
             i64 sA, i64 sB, i64 sC,
             const float* __restrict__ e0, const float* __restrict__ e1,
             const float* __restrict__ e2, const float* __restrict__ xres, i64 sX) {
  __shared__ u16 sm[2 * 32768];  // 128 KiB
  const int b = blockIdx.z;
  A += (size_t)b * sA;
  Bm += (size_t)b * sB;
  const size_t cbase = (size_t)b * sC;
  if constexpr (MODE == 3) xres += (size_t)b * sX;

  // T1: bijective XCD-chunked swizzle (m204) on the flattened (y,x) id.
  const int gx = gridDim.x;
  const int nwg = gx * gridDim.y;
  int flat = blockIdx.y * gx + blockIdx.x;
  {
    const int q = nwg >> 3, r = nwg & 7;
    const int xcd = flat & 7, sidx = flat >> 3;
    flat = (xcd < r ? xcd * (q + 1) : r * (q + 1) + (xcd - r) * q) + sidx;
  }
  const int i0 = (flat / gx) * 256;
  const int j0 = (flat % gx) * 256;

  const int tid = threadIdx.x;
  const int lane = tid & 63;
  const int wave = tid >> 6;  // 0..7
  const int wm = wave >> 2;   // 0..1 (M half)
  const int wn = wave & 3;    // 0..3 (N quarter)

  // ---- staging addresses (pre-swizzled global source, linear LDS dest) ----
  const int rs = tid >> 2;                                // chunk row 0..127
  const int swz = ((tid & 3) ^ ((rs >> 1) & 3)) * 8;      // swizzled col elems
  const u16* Ag0 = A + (size_t)(i0 + rs) * lda + swz;
  const u16* Bg0 = Bm + (size_t)(j0 + rs) * ldb + swz;
  const i64 ldA128 = (i64)128 * lda;
  const i64 ldB128 = (i64)128 * ldb;
  u16* ldsT = sm + tid * 8;  // per-wave: base + lane*16B (linear)

  auto stA = [&](int buf, int kh, int k0) {
    const u16* s = Ag0 + k0 + kh * 32;
    u16* d = ldsT + buf * 32768 + kh * 8192;
    load16(s, d);
    load16(s + ldA128, d + 4096);
  };
  auto stB = [&](int buf, int kh, int k0) {
    const u16* s = Bg0 + k0 + kh * 32;
    u16* d = ldsT + buf * 32768 + 16384 + kh * 8192;
    load16(s, d);
    load16(s + ldB128, d + 4096);
  };

  // ---- fragment read addressing ----
  const int l15 = lane & 15;
  const int slR = (((lane >> 4) ^ ((l15 >> 1) & 3)) * 8);  // swizzled 16B slot
  const int arow = wm * 128 + l15;  // + frag*16
  const int brow = wn * 64 + l15;   // + frag*16

  f32x4 acc[8][4] = {};

// one K-half: reads first (data guaranteed by an earlier sync), then stages,
// then the counted sync, then the MFMA cluster.
#define KHALF(BUF, KH, STG, SYNC)                                              \
  {                                                                            \
    const u16* Ab_ = sm + (BUF) * 32768 + (KH) * 8192;                         \
    const u16* Bb_ = Ab_ + 16384;                                              \
    bf16x8 bv[4], a0[4], a1[4];                                                \
    _Pragma("unroll") for (int n = 0; n < 4; ++n)                              \
        bv[n] = *(const bf16x8*)&Bb_[(brow + n * 16) * 32 + slR];              \
    _Pragma("unroll") for (int f = 0; f < 4; ++f)                              \
        a0[f] = *(const bf16x8*)&Ab_[(arow + f * 16) * 32 + slR];              \
    _Pragma("unroll") for (int f = 0; f < 4; ++f)                              \
        a1[f] = *(const bf16x8*)&Ab_[(arow + (f + 4) * 16) * 32 + slR];        \
    STG;                                                                       \
    SYNC                                                                       \
    __builtin_amdgcn_s_setprio(1);                                             \
    _Pragma("unroll") for (int f = 0; f < 4; ++f)                              \
        _Pragma("unroll") for (int n = 0; n < 4; ++n)                          \
            acc[f][n] = __builtin_amdgcn_mfma_f32_16x16x32_bf16(               \
                a0[f], bv[n], acc[f][n], 0, 0, 0);                             \
    _Pragma("unroll") for (int f = 0; f < 4; ++f)                              \
        _Pragma("unroll") for (int n = 0; n < 4; ++n)                          \
            acc[f + 4][n] = __builtin_amdgcn_mfma_f32_16x16x32_bf16(           \
                a1[f], bv[n], acc[f + 4][n], 0, 0, 0);                         \
    __builtin_amdgcn_s_setprio(0);                                             \
  }

  const int NT = K >> 6;  // >= 8 for all shapes here

  // prologue: U0_0(A,B), U1_0(A,B), U0_1(A,B) = 12 load-insts.
  // vmcnt(8) => U0_0 landed for all waves.
  stA(0, 0, 0); stB(0, 0, 0);
  stA(0, 1, 0); stB(0, 1, 0);
  stA(1, 0, 64); stB(1, 0, 64);
  SYNC_V(8);

  for (int t = 0; t < NT - 2; ++t) {
    const int bc = t & 1;
    const int k0 = t * 64;
    KHALF(bc, 0, { stA(bc ^ 1, 1, k0 + 64); stB(bc ^ 1, 1, k0 + 64); }, SYNC_V(8));
    KHALF(bc, 1, { stA(bc, 0, k0 + 128); stB(bc, 0, k0 + 128); }, SYNC_V(8));
  }
  {  // tail: last stage, then drain 8 -> 4 -> 0; final KHALF sync-free.
    const int bc = (NT - 2) & 1;
    KHALF(bc, 0, { stA(bc ^ 1, 1, (NT - 1) * 64); stB(bc ^ 1, 1, (NT - 1) * 64); }, SYNC_V(8));
    KHALF(bc, 1, { (void)0; }, SYNC_V(4));
    KHALF(bc ^ 1, 0, { (void)0; }, SYNC_V(0));
    KHALF(bc ^ 1, 1, { (void)0; }, );
  }
#undef KHALF

  // C/D layout (verified m89/m91): col = lane&15, row = (lane>>4)*4 + reg
  const int rr0 = i0 + wm * 128 + ((lane >> 4) << 2);
  const int cc0 = j0 + wn * 64 + (lane & 15);
  float* Cf = (float*)Cp;
  u16* Cs = (u16*)Cp;
#pragma unroll
  for (int mi = 0; mi < 8; ++mi) {
#pragma unroll
    for (int ni = 0; ni < 4; ++ni) {
      const int col = cc0 + ni * 16;
#pragma unroll
      for (int r = 0; r < 4; ++r) {
        const int row = rr0 + mi * 16 + r;
        const size_t idx = cbase + (size_t)row * ldc + col;
        float v = acc[mi][ni][r];
        if constexpr (MODE == 0) {
          Cs[idx] = f2bf(v + e0[col]);
        } else if constexpr (MODE == 1) {
          Cs[idx] = f2bf(v);
        } else {
          const float sc = e1[row] * rsqrtf(1.0f + 1e-5f);
          Cf[idx] = (v + e0[row]) * sc + e2[row] + xres[(size_t)row * ldc + col];
        }
      }
    }
  }
}

// x (b,C,N) fp32 -> Xt (b,N,C) bf16 (tiled transpose-cast); z = batch
__global__ __launch_bounds__(256)
void transpose_cast_x(const float* __restrict__ src, u16* __restrict__ dst) {
  __shared__ u16 tile[32][33];
  const size_t so = (size_t)blockIdx.z * C_ * N_;
  const int n0 = blockIdx.x * 32;
  const int c0 = blockIdx.y * 32;
  const int tx = threadIdx.x & 31;
  const int ty = threadIdx.x >> 5;  // 0..7
#pragma unroll
  for (int rr = 0; rr < 32; rr += 8)
    tile[ty + rr][tx] = f2bf(src[so + (size_t)(c0 + ty + rr) * N_ + n0 + tx]);
  __syncthreads();
#pragma unroll
  for (int rr = 0; rr < 32; rr += 8)
    dst[so + (size_t)(n0 + ty + rr) * C_ + c0 + tx] = tile[tx][ty + rr];
}

// bf16 transpose per batch: src (b, MP_, CI_) -> dst (b, CI_, MP_)
__global__ __launch_bounds__(256)
void transpose_bf16(const u16* __restrict__ src, u16* __restrict__ dst) {
  __shared__ u16 tile[32][33];
  const int b = blockIdx.z;
  const int c0 = blockIdx.x * 32;  // over CI_
  const int r0 = blockIdx.y * 32;  // over MP_
  const int tx = threadIdx.x & 31;
  const int ty = threadIdx.x >> 5;
#pragma unroll
  for (int rr = 0; rr < 32; rr += 8)
    tile[ty + rr][tx] = src[(size_t)b * MP_ * CI_ + (size_t)(r0 + ty + rr) * CI_ + c0 + tx];
  __syncthreads();
#pragma unroll
  for (int rr = 0; rr < 32; rr += 8)
    dst[(size_t)b * CI_ * MP_ + (size_t)(c0 + ty + rr) * MP_ + r0 + tx] = tile[tx][ty + rr];
}

// cast weights fp32->bf16 into fused layout: wcat rows [theta; g; phi], plus Ww
__global__ __launch_bounds__(256)
void cast_weights(const float* s0, const float* s1, const float* s2, const float* s3,
                  u16* d0, u16* d1, u16* d2, u16* d3) {
  const int idx = blockIdx.x * 256 + threadIdx.x;  // 524288 elems each
  const float* s;
  u16* d;
  switch (blockIdx.y) {
    case 0: s = s0; d = d0; break;
    case 1: s = s1; d = d1; break;
    case 2: s = s2; d = d2; break;
    default: s = s3; d = d3; break;
  }
  d[idx] = f2bf(s[idx]);
}

// pack [theta_b; g_b; phi_b] -> ebias fp32[1536]
__global__ __launch_bounds__(256)
void concat_bias(const float* tb, const float* gb, const float* pb, float* dst) {
  const int i = blockIdx.x * 256 + threadIdx.x;
  if (i >= C3_) return;
  dst[i] = (i < CI_) ? tb[i] : (i < 2 * CI_) ? gb[i - CI_] : pb[i - 2 * CI_];
}

// maxpool2 over (T,H,W): reads CO (b, N_, C3_) at col offset 512(g)/1024(phi),
// writes (b, MP_, CI_); pad rows (m >= M_) zeroed. grid: (MP_*CI_/256, 2, G)
__global__ __launch_bounds__(256)
void pool2(const u16* __restrict__ CO, u16* __restrict__ Gp, u16* __restrict__ Pp) {
  const int b = blockIdx.z;
  const int which = blockIdx.y;  // 0 = g, 1 = phi
  const u16* src = CO + (size_t)b * N_ * C3_ + CI_ + which * CI_;
  u16* dst = (which ? Pp : Gp) + (size_t)b * MP_ * CI_;
  const int idx = blockIdx.x * 256 + threadIdx.x;  // over MP_*CI_
  const int m = idx >> 9;
  const int ci = idx & 511;
  if (m >= M_) { dst[idx] = 0; return; }
  const int t = m / 196, r = m % 196, h = r / 14, w = r % 14;
  const int nb = 2 * t * 784 + 2 * h * 28 + 2 * w;
  float mx = -1e30f;
#pragma unroll
  for (int dt = 0; dt < 2; ++dt)
#pragma unroll
    for (int dh = 0; dh < 2; ++dh)
#pragma unroll
      for (int dw = 0; dw < 2; ++dw)
        mx = fmaxf(mx, bf2f(src[(size_t)(nb + dt * 784 + dh * 28 + dw) * C3_ + ci]));
  dst[idx] = f2bf(mx);
}

// in-place row softmax (bf16) over m<M_ of F (b, N_, MP_).
// M_ = 1568 = 196*8 exactly: 196 threads handle one u16x8 (16B coalesced)
// each; pad cols [1568,1792) are exactly 0 from the logits GEMM (Pp pad rows
// are zeroed) and are left untouched.
__global__ __launch_bounds__(256)
void softmax_k(u16* __restrict__ F) {
  u16* row = F + ((size_t)blockIdx.y * N_ + blockIdx.x) * MP_;
  const int tid = threadIdx.x;
  const bool valid = tid < 196;
  float v[8];
  float mx = -1e30f;
  if (valid) {
    u16x8v pk = *(const u16x8v*)&row[tid * 8];
#pragma unroll
    for (int i = 0; i < 8; ++i) { v[i] = bf2f(pk[i]); mx = fmaxf(mx, v[i]); }
  }
#pragma unroll
  for (int off = 32; off >= 1; off >>= 1) mx = fmaxf(mx, __shfl_xor(mx, off));
  __shared__ float redm[4], reds[4];
  const int wv = tid >> 6;
  if ((tid & 63) == 0) redm[wv] = mx;
  __syncthreads();
  mx = fmaxf(fmaxf(redm[0], redm[1]), fmaxf(redm[2], redm[3]));
  float s = 0.f;
  if (valid) {
#pragma unroll
    for (int i = 0; i < 8; ++i) { v[i] = __expf(v[i] - mx); s += v[i]; }
  }
#pragma unroll
  for (int off = 32; off >= 1; off >>= 1) s += __shfl_xor(s, off);
  if ((tid & 63) == 0) reds[wv] = s;
  __syncthreads();
  const float inv = 1.f / (reds[0] + reds[1] + reds[2] + reds[3]);
  if (valid) {
    u16x8v pk;
#pragma unroll
    for (int i = 0; i < 8; ++i) pk[i] = f2bf(v[i] * inv);
    *(u16x8v*)&row[tid * 8] = pk;
  }
}

extern "C" void kernel_launch(void* const* d_in, const int* in_sizes, int n_in,
                              void* d_out, int out_size, void* d_ws, size_t ws_size,
                              hipStream_t stream) {
  (void)in_sizes; (void)n_in; (void)out_size;
  const float* x    = (const float*)d_in[0];
  const float* g_w  = (const float*)d_in[1];
  const float* g_b  = (const float*)d_in[2];
  const float* th_w = (const float*)d_in[3];
  const float* th_b = (const float*)d_in[4];
  const float* ph_w = (const float*)d_in[5];
  const float* ph_b = (const float*)d_in[6];
  const float* w_w  = (const float*)d_in[7];
  const float* w_b  = (const float*)d_in[8];
  const float* bn_g = (const float*)d_in[9];
  const float* bn_b = (const float*)d_in[10];
  float* out = (float*)d_out;

  auto align256 = [](size_t b) { return (b + 255) & ~(size_t)255; };
  const size_t fixed_bytes = align256((size_t)C3_ * C_ * 2) + align256((size_t)C_ * CI_ * 2) +
                             align256((size_t)C3_ * 4);
  const size_t per_batch = align256((size_t)N_ * C_ * 2)    // Xt
                         + align256((size_t)N_ * C3_ * 2)   // CO
                         + align256((size_t)N_ * MP_ * 2)   // F / P
                         + align256((size_t)N_ * CI_ * 2)   // Yb
                         + 3 * align256((size_t)MP_ * CI_ * 2);  // Gp, Pp, Gp2
  int G = 4;
  while (G > 1 && fixed_bytes + (size_t)G * per_batch > ws_size) G >>= 1;

  char* ws = (char*)d_ws;
  size_t off = 0;
  auto alloc = [&](size_t bytes) -> void* {
    void* p = ws + off;
    off += align256(bytes);
    return p;
  };
  u16* wcat = (u16*)alloc((size_t)C3_ * C_ * 2);   // rows: [theta; g; phi]
  u16* wwB  = (u16*)alloc((size_t)C_ * CI_ * 2);
  float* eb = (float*)alloc((size_t)C3_ * 4);
  u16* Xt  = (u16*)alloc((size_t)G * N_ * C_ * 2);
  u16* CO  = (u16*)alloc((size_t)G * N_ * C3_ * 2);
  u16* Fb  = (u16*)alloc((size_t)G * N_ * MP_ * 2);  // logits, then probs in-place
  u16* Yb  = (u16*)alloc((size_t)G * N_ * CI_ * 2);
  u16* Gp  = (u16*)alloc((size_t)G * MP_ * CI_ * 2);
  u16* Pp  = (u16*)alloc((size_t)G * MP_ * CI_ * 2);
  u16* Gp2 = (u16*)alloc((size_t)G * CI_ * MP_ * 2);

  const dim3 blk(256);
  const dim3 gblk(512);
  cast_weights<<<dim3(2048, 4), blk, 0, stream>>>(
      th_w, g_w, ph_w, w_w, wcat, wcat + (size_t)CI_ * C_, wcat + (size_t)2 * CI_ * C_, wwB);
  concat_bias<<<dim3(6), blk, 0, stream>>>(th_b, g_b, ph_b, eb);

  for (int bg = 0; bg < B_; bg += G) {
    const float* xg = x + (size_t)bg * C_ * N_;
    float* og = out + (size_t)bg * C_ * N_;
    transpose_cast_x<<<dim3(N_ / 32, C_ / 32, G), blk, 0, stream>>>(xg, Xt);
    // fused 1x1 convs: CO(G*N, C3) = Xt(G*N, C) . wcat(C3, C)^T + eb  (batches stacked)
    gemm_tn<0><<<dim3(C3_ / 256, G * N_ / 256, 1), gblk, 0, stream>>>(
        Xt, wcat, CO, C_, C_, C_, C3_, 0, 0, 0, eb, nullptr, nullptr, nullptr, 0);
    pool2<<<dim3(MP_ * CI_ / 256, 2, G), blk, 0, stream>>>(CO, Gp, Pp);
    transpose_bf16<<<dim3(CI_ / 32, MP_ / 32, G), blk, 0, stream>>>(Gp, Gp2);
    // logits: F(b; N, MP) = Th(b; N, CI [lda=C3]) . Pp(b; MP, CI)^T
    gemm_tn<1><<<dim3(MP_ / 256, N_ / 256, G), gblk, 0, stream>>>(
        CO, Pp, Fb, CI_, C3_, CI_, MP_,
        (i64)N_ * C3_, (i64)MP_ * CI_, (i64)N_ * MP_, nullptr, nullptr, nullptr, nullptr, 0);
    softmax_k<<<dim3(N_, G), blk, 0, stream>>>(Fb);
    // y: Yb(b; N, CI) = P(b; N, MP) . Gp2(b; CI, MP)^T
    gemm_tn<1><<<dim3(CI_ / 256, N_ / 256, G), gblk, 0, stream>>>(
        Fb, Gp2, Yb, MP_, MP_, MP_, CI_,
        (i64)N_ * MP_, (i64)CI_ * MP_, (i64)N_ * CI_, nullptr, nullptr, nullptr, nullptr, 0);
    // out: (b; C, N) = Ww(C, CI) . Yb(b; N, CI)^T, epilogue bias/BN/residual
    gemm_tn<3><<<dim3(N_ / 256, C_ / 256, G), gblk, 0, stream>>>(
        wwB, Yb, og, CI_, CI_, CI_, N_,
        0, (i64)N_ * CI_, (i64)C_ * N_, w_b, bn_g, bn_b, xg, (i64)C_ * N_);
  }
}

// Round 3
// 967.148 us; speedup vs baseline: 1.2325x; 1.0257x over previous
//
#include <hip/hip_runtime.h>

#define DEVI __device__ __forceinline__

typedef __bf16 bf16x8 __attribute__((ext_vector_type(8)));
typedef float f32x4 __attribute__((ext_vector_type(4)));
typedef unsigned short u16;
typedef u16 u16x8v __attribute__((ext_vector_type(8)));
typedef long long i64;

constexpr int B_ = 4;
constexpr int C_ = 1024;
constexpr int CI_ = 512;
constexpr int C3_ = 3 * CI_;       // 1536 fused conv output cols
constexpr int N_ = 16 * 28 * 28;   // 12544 = 49*256
constexpr int M_ = 8 * 14 * 14;    // 1568 = 196*8
constexpr int MP_ = 1792;          // 7*256 padded

DEVI u16 f2bf(float f) { __bf16 b = (__bf16)f; return __builtin_bit_cast(u16, b); }
DEVI float bf2f(u16 u) { return (float)__builtin_bit_cast(__bf16, u); }

#define GLOBAL_AS __attribute__((address_space(1)))
#define LDS_AS __attribute__((address_space(3)))

DEVI void load16(const u16* g, u16* l) {
  __builtin_amdgcn_global_load_lds((const GLOBAL_AS void*)g, (LDS_AS void*)l, 16, 0, 0);
}

// counted-vmcnt + barrier sync (round-1 shape: no sched_barrier fence; the
// "memory" clobbers pin LDS reads / global_load_lds on their program-order
// side, and the compiler keeps its own fine-grained lgkmcnt scheduling).
#define SYNC_V(N)                                        \
  asm volatile("s_waitcnt vmcnt(" #N ")" ::: "memory");  \
  __builtin_amdgcn_s_barrier();                          \
  asm volatile("" ::: "memory");

// ---------------------------------------------------------------------------
// Universal batched TN GEMM, 256x256 tile, BK=64, 512 threads (8 waves, 2Mx4N),
// MFMA 16x16x32 bf16, counted-vmcnt schedule (T1+T2+T3+T4+T5).
//
// LDS (128 KiB): [buf:2][mat A|B][kh:2][row:256][8 bf16 x 4 slots]
//   Bank swizzle: 16B slot index XORed with (row>>1)&3 on BOTH the global
//   staging source and the ds_read address (rule #21 involution) => 2
//   lanes/bank on ds_read_b128, conflict-free (verified: SQ_LDS_BANK_CONFLICT
//   = 0 in rounds 1-2).
//
// KHALF (round-1 interleaved shape — measured better than reads-before-sync):
//   read bv[4]+a0[4]; stage A(next); 16 MFMA; read a1[4]; stage B(next);
//   16 MFMA; s_waitcnt vmcnt(8); s_barrier
// Guarantee chain (4 load-insts per KHALF, counted-8 window): at each sync
// exactly the youngest 8 load-insts (next 1.5 units) stay in flight; the
// kh-half read next is always older => landed. WAR: each overwritten slot's
// last read precedes the barrier before its stage issue. vmcnt(0) only once,
// in the tail.
//
// MODE 0: bf16 out = acc + e0[col];  MODE 1: bf16 out = acc
// MODE 3: fp32 out = (acc+e0[row])*e1[row]*rsqrt(1+eps) + e2[row] + xres
// ---------------------------------------------------------------------------
template <int MODE>
__global__ __launch_bounds__(512, 2)
void gemm_tn(const u16* __restrict__ A, const u16* __restrict__ Bm,
             void* __restrict__ Cp, int K, int lda, int ldb, int ldc,
             i64 sA, i64 sB, i64 sC,
             const float* __restrict__ e0, const float* __restrict__ e1,
             const float* __restrict__ e2, const float* __restrict__ xres, i64 sX) {
  __shared__ u16 sm[2 * 32768];  // 128 KiB
  const int b = blockIdx.z;
  A += (size_t)b * sA;
  Bm += (size_t)b * sB;
  const size_t cbase = (size_t)b * sC;
  if constexpr (MODE == 3) xres += (size_t)b * sX;

  // T1: bijective XCD-chunked swizzle (m204) on the flattened (y,x) id.
  const int gx = gridDim.x;
  const int nwg = gx * gridDim.y;
  int flat = blockIdx.y * gx + blockIdx.x;
  {
    const int q = nwg >> 3, r = nwg & 7;
    const int xcd = flat & 7, sidx = flat >> 3;
    flat = (xcd < r ? xcd * (q + 1) : r * (q + 1) + (xcd - r) * q) + sidx;
  }
  const int i0 = (flat / gx) * 256;
  const int j0 = (flat % gx) * 256;

  const int tid = threadIdx.x;
  const int lane = tid & 63;
  const int wave = tid >> 6;  // 0..7
  const int wm = wave >> 2;   // 0..1 (M half)
  const int wn = wave & 3;    // 0..3 (N quarter)

  // ---- staging addresses (pre-swizzled global source, linear LDS dest) ----
  const int rs = tid >> 2;                                // chunk row 0..127
  const int swz = ((tid & 3) ^ ((rs >> 1) & 3)) * 8;      // swizzled col elems
  const u16* Ag0 = A + (size_t)(i0 + rs) * lda + swz;
  const u16* Bg0 = Bm + (size_t)(j0 + rs) * ldb + swz;
  const i64 ldA128 = (i64)128 * lda;
  const i64 ldB128 = (i64)128 * ldb;
  u16* ldsT = sm + tid * 8;  // per-wave: base + lane*16B (linear)

  auto stA = [&](int buf, int kh, int k0) {
    const u16* s = Ag0 + k0 + kh * 32;
    u16* d = ldsT + buf * 32768 + kh * 8192;
    load16(s, d);
    load16(s + ldA128, d + 4096);
  };
  auto stB = [&](int buf, int kh, int k0) {
    const u16* s = Bg0 + k0 + kh * 32;
    u16* d = ldsT + buf * 32768 + 16384 + kh * 8192;
    load16(s, d);
    load16(s + ldB128, d + 4096);
  };

  // ---- fragment read addressing ----
  const int l15 = lane & 15;
  const int slR = (((lane >> 4) ^ ((l15 >> 1) & 3)) * 8);  // swizzled 16B slot
  const int arow = wm * 128 + l15;  // + frag*16
  const int brow = wn * 64 + l15;   // + frag*16

  f32x4 acc[8][4] = {};

// one K-half, round-1 interleave: stages sit between read blocks and MFMA
// clusters; a1 reads overlap MFMA cluster 1 in the compiler's schedule.
#define KHALF(BUF, KH, S1, S2, SYNC)                                           \
  {                                                                            \
    const u16* Ab_ = sm + (BUF) * 32768 + (KH) * 8192;                         \
    const u16* Bb_ = Ab_ + 16384;                                              \
    bf16x8 bv[4], a0[4], a1[4];                                                \
    _Pragma("unroll") for (int n = 0; n < 4; ++n)                              \
        bv[n] = *(const bf16x8*)&Bb_[(brow + n * 16) * 32 + slR];              \
    _Pragma("unroll") for (int f = 0; f < 4; ++f)                              \
        a0[f] = *(const bf16x8*)&Ab_[(arow + f * 16) * 32 + slR];              \
    S1;                                                                        \
    __builtin_amdgcn_s_setprio(1);                                             \
    _Pragma("unroll") for (int f = 0; f < 4; ++f)                              \
        _Pragma("unroll") for (int n = 0; n < 4; ++n)                          \
            acc[f][n] = __builtin_amdgcn_mfma_f32_16x16x32_bf16(               \
                a0[f], bv[n], acc[f][n], 0, 0, 0);                             \
    __builtin_amdgcn_s_setprio(0);                                             \
    _Pragma("unroll") for (int f = 0; f < 4; ++f)                              \
        a1[f] = *(const bf16x8*)&Ab_[(arow + (f + 4) * 16) * 32 + slR];        \
    S2;                                                                        \
    __builtin_amdgcn_s_setprio(1);                                             \
    _Pragma("unroll") for (int f = 0; f < 4; ++f)                              \
        _Pragma("unroll") for (int n = 0; n < 4; ++n)                          \
            acc[f + 4][n] = __builtin_amdgcn_mfma_f32_16x16x32_bf16(           \
                a1[f], bv[n], acc[f + 4][n], 0, 0, 0);                         \
    __builtin_amdgcn_s_setprio(0);                                             \
    SYNC                                                                       \
  }

  const int NT = K >> 6;  // >= 8 for all shapes here

  // prologue: U0_0(A,B), U1_0(A,B), U0_1(A,B) = 12 load-insts.
  // vmcnt(8) => first 4 (U0_0) landed, which is all tile-0/kh0 needs.
  stA(0, 0, 0); stB(0, 0, 0);
  stA(0, 1, 0); stB(0, 1, 0);
  stA(1, 0, 64); stB(1, 0, 64);
  SYNC_V(8);

  for (int t = 0; t < NT - 2; ++t) {
    const int bc = t & 1;
    const int k0 = t * 64;
    KHALF(bc, 0, stA(bc ^ 1, 1, k0 + 64), stB(bc ^ 1, 1, k0 + 64), SYNC_V(8));
    KHALF(bc, 1, stA(bc, 0, k0 + 128), stB(bc, 0, k0 + 128), SYNC_V(8));
  }
  {  // tail: stage U1_{NT-1}, drain once, compute last 2 tiles
    const int bc = (NT - 2) & 1;
    stA(bc ^ 1, 1, (NT - 1) * 64);
    stB(bc ^ 1, 1, (NT - 1) * 64);
    SYNC_V(0);
    KHALF(bc, 0, (void)0, (void)0, );
    KHALF(bc, 1, (void)0, (void)0, );
    KHALF(bc ^ 1, 0, (void)0, (void)0, );
    KHALF(bc ^ 1, 1, (void)0, (void)0, );
  }
#undef KHALF

  // C/D layout (verified m89/m91): col = lane&15, row = (lane>>4)*4 + reg
  const int rr0 = i0 + wm * 128 + ((lane >> 4) << 2);
  const int cc0 = j0 + wn * 64 + (lane & 15);
  float* Cf = (float*)Cp;
  u16* Cs = (u16*)Cp;
#pragma unroll
  for (int mi = 0; mi < 8; ++mi) {
#pragma unroll
    for (int ni = 0; ni < 4; ++ni) {
      const int col = cc0 + ni * 16;
#pragma unroll
      for (int r = 0; r < 4; ++r) {
        const int row = rr0 + mi * 16 + r;
        const size_t idx = cbase + (size_t)row * ldc + col;
        float v = acc[mi][ni][r];
        if constexpr (MODE == 0) {
          Cs[idx] = f2bf(v + e0[col]);
        } else if constexpr (MODE == 1) {
          Cs[idx] = f2bf(v);
        } else {
          const float sc = e1[row] * rsqrtf(1.0f + 1e-5f);
          Cf[idx] = (v + e0[row]) * sc + e2[row] + xres[(size_t)row * ldc + col];
        }
      }
    }
  }
}

// x (b,C,N) fp32 -> Xt (b,N,C) bf16 (tiled transpose-cast); z = batch
__global__ __launch_bounds__(256)
void transpose_cast_x(const float* __restrict__ src, u16* __restrict__ dst) {
  __shared__ u16 tile[32][33];
  const size_t so = (size_t)blockIdx.z * C_ * N_;
  const int n0 = blockIdx.x * 32;
  const int c0 = blockIdx.y * 32;
  const int tx = threadIdx.x & 31;
  const int ty = threadIdx.x >> 5;  // 0..7
#pragma unroll
  for (int rr = 0; rr < 32; rr += 8)
    tile[ty + rr][tx] = f2bf(src[so + (size_t)(c0 + ty + rr) * N_ + n0 + tx]);
  __syncthreads();
#pragma unroll
  for (int rr = 0; rr < 32; rr += 8)
    dst[so + (size_t)(n0 + ty + rr) * C_ + c0 + tx] = tile[tx][ty + rr];
}

// bf16 transpose per batch: src (b, MP_, CI_) -> dst (b, CI_, MP_)
__global__ __launch_bounds__(256)
void transpose_bf16(const u16* __restrict__ src, u16* __restrict__ dst) {
  __shared__ u16 tile[32][33];
  const int b = blockIdx.z;
  const int c0 = blockIdx.x * 32;  // over CI_
  const int r0 = blockIdx.y * 32;  // over MP_
  const int tx = threadIdx.x & 31;
  const int ty = threadIdx.x >> 5;
#pragma unroll
  for (int rr = 0; rr < 32; rr += 8)
    tile[ty + rr][tx] = src[(size_t)b * MP_ * CI_ + (size_t)(r0 + ty + rr) * CI_ + c0 + tx];
  __syncthreads();
#pragma unroll
  for (int rr = 0; rr < 32; rr += 8)
    dst[(size_t)b * CI_ * MP_ + (size_t)(c0 + ty + rr) * MP_ + r0 + tx] = tile[tx][ty + rr];
}

// cast weights fp32->bf16 into fused layout: wcat rows [theta; g; phi], plus Ww
__global__ __launch_bounds__(256)
void cast_weights(const float* s0, const float* s1, const float* s2, const float* s3,
                  u16* d0, u16* d1, u16* d2, u16* d3) {
  const int idx = blockIdx.x * 256 + threadIdx.x;  // 524288 elems each
  const float* s;
  u16* d;
  switch (blockIdx.y) {
    case 0: s = s0; d = d0; break;
    case 1: s = s1; d = d1; break;
    case 2: s = s2; d = d2; break;
    default: s = s3; d = d3; break;
  }
  d[idx] = f2bf(s[idx]);
}

// pack [theta_b; g_b; phi_b] -> ebias fp32[1536]
__global__ __launch_bounds__(256)
void concat_bias(const float* tb, const float* gb, const float* pb, float* dst) {
  const int i = blockIdx.x * 256 + threadIdx.x;
  if (i >= C3_) return;
  dst[i] = (i < CI_) ? tb[i] : (i < 2 * CI_) ? gb[i - CI_] : pb[i - 2 * CI_];
}

// maxpool2 over (T,H,W): reads CO (b, N_, C3_) at col offset 512(g)/1024(phi),
// writes (b, MP_, CI_); pad rows (m >= M_) zeroed. grid: (MP_*CI_/256, 2, G)
__global__ __launch_bounds__(256)
void pool2(const u16* __restrict__ CO, u16* __restrict__ Gp, u16* __restrict__ Pp) {
  const int b = blockIdx.z;
  const int which = blockIdx.y;  // 0 = g, 1 = phi
  const u16* src = CO + (size_t)b * N_ * C3_ + CI_ + which * CI_;
  u16* dst = (which ? Pp : Gp) + (size_t)b * MP_ * CI_;
  const int idx = blockIdx.x * 256 + threadIdx.x;  // over MP_*CI_
  const int m = idx >> 9;
  const int ci = idx & 511;
  if (m >= M_) { dst[idx] = 0; return; }
  const int t = m / 196, r = m % 196, h = r / 14, w = r % 14;
  const int nb = 2 * t * 784 + 2 * h * 28 + 2 * w;
  float mx = -1e30f;
#pragma unroll
  for (int dt = 0; dt < 2; ++dt)
#pragma unroll
    for (int dh = 0; dh < 2; ++dh)
#pragma unroll
      for (int dw = 0; dw < 2; ++dw)
        mx = fmaxf(mx, bf2f(src[(size_t)(nb + dt * 784 + dh * 28 + dw) * C3_ + ci]));
  dst[idx] = f2bf(mx);
}

// in-place row softmax (bf16) over m<M_ of F (b, N_, MP_).
// M_ = 1568 = 196*8 exactly: 196 threads handle one u16x8 (16B coalesced)
// each; pad cols [1568,1792) are exactly 0 from the logits GEMM (Pp pad rows
// are zeroed) and are left untouched.
__global__ __launch_bounds__(256)
void softmax_k(u16* __restrict__ F) {
  u16* row = F + ((size_t)blockIdx.y * N_ + blockIdx.x) * MP_;
  const int tid = threadIdx.x;
  const bool valid = tid < 196;
  float v[8];
  float mx = -1e30f;
  if (valid) {
    u16x8v pk = *(const u16x8v*)&row[tid * 8];
#pragma unroll
    for (int i = 0; i < 8; ++i) { v[i] = bf2f(pk[i]); mx = fmaxf(mx, v[i]); }
  }
#pragma unroll
  for (int off = 32; off >= 1; off >>= 1) mx = fmaxf(mx, __shfl_xor(mx, off));
  __shared__ float redm[4], reds[4];
  const int wv = tid >> 6;
  if ((tid & 63) == 0) redm[wv] = mx;
  __syncthreads();
  mx = fmaxf(fmaxf(redm[0], redm[1]), fmaxf(redm[2], redm[3]));
  float s = 0.f;
  if (valid) {
#pragma unroll
    for (int i = 0; i < 8; ++i) { v[i] = __expf(v[i] - mx); s += v[i]; }
  }
#pragma unroll
  for (int off = 32; off >= 1; off >>= 1) s += __shfl_xor(s, off);
  if ((tid & 63) == 0) reds[wv] = s;
  __syncthreads();
  const float inv = 1.f / (reds[0] + reds[1] + reds[2] + reds[3]);
  if (valid) {
    u16x8v pk;
#pragma unroll
    for (int i = 0; i < 8; ++i) pk[i] = f2bf(v[i] * inv);
    *(u16x8v*)&row[tid * 8] = pk;
  }
}

extern "C" void kernel_launch(void* const* d_in, const int* in_sizes, int n_in,
                              void* d_out, int out_size, void* d_ws, size_t ws_size,
                              hipStream_t stream) {
  (void)in_sizes; (void)n_in; (void)out_size;
  const float* x    = (const float*)d_in[0];
  const float* g_w  = (const float*)d_in[1];
  const float* g_b  = (const float*)d_in[2];
  const float* th_w = (const float*)d_in[3];
  const float* th_b = (const float*)d_in[4];
  const float* ph_w = (const float*)d_in[5];
  const float* ph_b = (const float*)d_in[6];
  const float* w_w  = (const float*)d_in[7];
  const float* w_b  = (const float*)d_in[8];
  const float* bn_g = (const float*)d_in[9];
  const float* bn_b = (const float*)d_in[10];
  float* out = (float*)d_out;

  auto align256 = [](size_t b) { return (b + 255) & ~(size_t)255; };
  const size_t fixed_bytes = align256((size_t)C3_ * C_ * 2) + align256((size_t)C_ * CI_ * 2) +
                             align256((size_t)C3_ * 4);
  const size_t per_batch = align256((size_t)N_ * C_ * 2)    // Xt
                         + align256((size_t)N_ * C3_ * 2)   // CO
                         + align256((size_t)N_ * MP_ * 2)   // F / P
                         + align256((size_t)N_ * CI_ * 2)   // Yb
                         + 3 * align256((size_t)MP_ * CI_ * 2);  // Gp, Pp, Gp2
  int G = 4;
  while (G > 1 && fixed_bytes + (size_t)G * per_batch > ws_size) G >>= 1;

  char* ws = (char*)d_ws;
  size_t off = 0;
  auto alloc = [&](size_t bytes) -> void* {
    void* p = ws + off;
    off += align256(bytes);
    return p;
  };
  u16* wcat = (u16*)alloc((size_t)C3_ * C_ * 2);   // rows: [theta; g; phi]
  u16* wwB  = (u16*)alloc((size_t)C_ * CI_ * 2);
  float* eb = (float*)alloc((size_t)C3_ * 4);
  u16* Xt  = (u16*)alloc((size_t)G * N_ * C_ * 2);
  u16* CO  = (u16*)alloc((size_t)G * N_ * C3_ * 2);
  u16* Fb  = (u16*)alloc((size_t)G * N_ * MP_ * 2);  // logits, then probs in-place
  u16* Yb  = (u16*)alloc((size_t)G * N_ * CI_ * 2);
  u16* Gp  = (u16*)alloc((size_t)G * MP_ * CI_ * 2);
  u16* Pp  = (u16*)alloc((size_t)G * MP_ * CI_ * 2);
  u16* Gp2 = (u16*)alloc((size_t)G * CI_ * MP_ * 2);

  const dim3 blk(256);
  const dim3 gblk(512);
  cast_weights<<<dim3(2048, 4), blk, 0, stream>>>(
      th_w, g_w, ph_w, w_w, wcat, wcat + (size_t)CI_ * C_, wcat + (size_t)2 * CI_ * C_, wwB);
  concat_bias<<<dim3(6), blk, 0, stream>>>(th_b, g_b, ph_b, eb);

  for (int bg = 0; bg < B_; bg += G) {
    const float* xg = x + (size_t)bg * C_ * N_;
    float* og = out + (size_t)bg * C_ * N_;
    transpose_cast_x<<<dim3(N_ / 32, C_ / 32, G), blk, 0, stream>>>(xg, Xt);
    // fused 1x1 convs: CO(G*N, C3) = Xt(G*N, C) . wcat(C3, C)^T + eb  (batches stacked)
    gemm_tn<0><<<dim3(C3_ / 256, G * N_ / 256, 1), gblk, 0, stream>>>(
        Xt, wcat, CO, C_, C_, C_, C3_, 0, 0, 0, eb, nullptr, nullptr, nullptr, 0);
    pool2<<<dim3(MP_ * CI_ / 256, 2, G), blk, 0, stream>>>(CO, Gp, Pp);
    transpose_bf16<<<dim3(CI_ / 32, MP_ / 32, G), blk, 0, stream>>>(Gp, Gp2);
    // logits: F(b; N, MP) = Th(b; N, CI [lda=C3]) . Pp(b; MP, CI)^T
    gemm_tn<1><<<dim3(MP_ / 256, N_ / 256, G), gblk, 0, stream>>>(
        CO, Pp, Fb, CI_, C3_, CI_, MP_,
        (i64)N_ * C3_, (i64)MP_ * CI_, (i64)N_ * MP_, nullptr, nullptr, nullptr, nullptr, 0);
    softmax_k<<<dim3(N_, G), blk, 0, stream>>>(Fb);
    // y: Yb(b; N, CI) = P(b; N, MP) . Gp2(b; CI, MP)^T
    gemm_tn<1><<<dim3(CI_ / 256, N_ / 256, G), gblk, 0, stream>>>(
        Fb, Gp2, Yb, MP_, MP_, MP_, CI_,
        (i64)N_ * MP_, (i64)CI_ * MP_, (i64)N_ * CI_, nullptr, nullptr, nullptr, nullptr, 0);
    // out: (b; C, N) = Ww(C, CI) . Yb(b; N, CI)^T, epilogue bias/BN/residual
    gemm_tn<3><<<dim3(N_ / 256, C_ / 256, G), gblk, 0, stream>>>(
        wwB, Yb, og, CI_, CI_, CI_, N_,
        0, (i64)N_ * CI_, (i64)C_ * N_, w_b, bn_g, bn_b, xg, (i64)C_ * N_);
  }
}